// Round 4
// baseline (450.603 us; speedup 1.0000x reference)
//
#include <hip/hip_runtime.h>
#include <cstdint>
#include <cstddef>
#include <math.h>

typedef __attribute__((ext_vector_type(8))) __bf16 bf16x8;
typedef __attribute__((ext_vector_type(4))) __bf16 bf16x4;
typedef __attribute__((ext_vector_type(4))) float f32x4;

#define AS1 __attribute__((address_space(1)))
#define AS3 __attribute__((address_space(3)))

#define LOG2E 1.4426950408889634f

__device__ __forceinline__ void gld16(void* lds_uniform, const void* gaddr) {
  __builtin_amdgcn_global_load_lds((const AS1 unsigned int*)gaddr,
                                   (AS3 unsigned int*)lds_uniform, 16, 0, 0);
}

// ---------------------------------------------------------------- fp32->bf16 (with scale)
__global__ void cvt_kernel(const float* __restrict__ src, __bf16* __restrict__ dst, int n,
                           float scale) {
  int i = (blockIdx.x * 256 + threadIdx.x) * 4;
  if (i < n) {
    const float4 v = *(const float4*)(src + i);
    bf16x4 o;
    o[0] = (__bf16)(v.x * scale); o[1] = (__bf16)(v.y * scale);
    o[2] = (__bf16)(v.z * scale); o[3] = (__bf16)(v.w * scale);
    *(bf16x4*)(dst + i) = o;
  }
}

// ---------------------------------------------------------------- QKV GEMM
// Fused epilogue: bias, L2-norm, q*=exp(min(sm,ln100))*log2e; K written directly in
// attn fragment-tile order (ktp), Q in row order (qb), V in row order (vb).
__global__ __launch_bounds__(256, 2)
void gemm_qkv_kernel(const __bf16* __restrict__ A, const __bf16* __restrict__ B,
                     const float* __restrict__ q_bias, const float* __restrict__ v_bias,
                     const float* __restrict__ scale_mul,
                     __bf16* __restrict__ qb, __bf16* __restrict__ ktp, __bf16* __restrict__ vb) {
  __shared__ __attribute__((aligned(16))) __bf16 As[128 * 32];
  __shared__ __attribute__((aligned(16))) __bf16 Bs[128 * 32];
  const int tid = threadIdx.x;
  const int w = tid >> 6, lane = tid & 63;
  const int m0 = blockIdx.y * 128, n0 = blockIdx.x * 128;
  const int wm = (w >> 1) * 64, wn = (w & 1) * 64;
  const int c = lane & 15, g = lane >> 4;
  f32x4 acc[4][4];
#pragma unroll
  for (int i = 0; i < 4; ++i)
#pragma unroll
    for (int j = 0; j < 4; ++j) acc[i][j] = (f32x4)(0.0f);

  const int r_row = lane >> 2;
  const int r_col = (lane & 3) * 16;
  const char* Abase = (const char*)A + (size_t)m0 * 2048;
  const char* Bbase = (const char*)B + (size_t)n0 * 2048;

  for (int kt = 0; kt < 1024; kt += 32) {
#pragma unroll
    for (int s = 0; s < 2; ++s) {
      const int R = w * 2 + s;
      const int row = R * 16 + r_row;
      gld16((char*)As + R * 1024, Abase + (size_t)row * 2048 + kt * 2 + r_col);
      gld16((char*)Bs + R * 1024, Bbase + (size_t)row * 2048 + kt * 2 + r_col);
    }
    __syncthreads();
    bf16x8 af[4], bfr[4];
#pragma unroll
    for (int i = 0; i < 4; ++i) {
      af[i]  = *(const bf16x8*)((const char*)As + (wm + i * 16 + c) * 64 + g * 16);
      bfr[i] = *(const bf16x8*)((const char*)Bs + (wn + i * 16 + c) * 64 + g * 16);
    }
#pragma unroll
    for (int mi = 0; mi < 4; ++mi)
#pragma unroll
      for (int ni = 0; ni < 4; ++ni)
        acc[mi][ni] = __builtin_amdgcn_mfma_f32_16x16x32_bf16(af[mi], bfr[ni], acc[mi][ni], 0, 0, 0);
    __syncthreads();
  }

  const int nbase = n0 + wn;
  const int which = nbase >> 10;
  const int h = (nbase >> 6) & 15;
  float smh = 1.0f;
  if (which == 0) smh = __expf(fminf(scale_mul[h], 4.605170185988091f)) * LOG2E;
  float cbias[4];
#pragma unroll
  for (int ni = 0; ni < 4; ++ni) {
    const int n = nbase + ni * 16 + c;
    cbias[ni] = (which == 0) ? q_bias[n] : ((which == 2) ? v_bias[n - 2048] : 0.0f);
  }
#pragma unroll
  for (int mi = 0; mi < 4; ++mi) {
#pragma unroll
    for (int j = 0; j < 4; ++j) {
      const int m = m0 + wm + mi * 16 + g * 4 + j;
      float v[4];
      float ss = 0.0f;
#pragma unroll
      for (int ni = 0; ni < 4; ++ni) { v[ni] = acc[mi][ni][j] + cbias[ni]; ss += v[ni] * v[ni]; }
      ss += __shfl_xor(ss, 1, 64);
      ss += __shfl_xor(ss, 2, 64);
      ss += __shfl_xor(ss, 4, 64);
      ss += __shfl_xor(ss, 8, 64);
      const float sc = (which == 2) ? 1.0f : (rsqrtf(ss) * smh);
      const int b2 = m >> 11, lpos = m & 2047;
      if (which == 1) {
        // K -> fragment-tile order: bh*131072 + (l>>6)*4096 + (hd>>5)*2048 + (l&63)*32 + (hd&31)
        __bf16* kt_base = ktp + (size_t)(b2 * 16 + h) * 131072 +
                          (size_t)(lpos >> 6) * 4096 + (size_t)(lpos & 63) * 32;
#pragma unroll
        for (int ni = 0; ni < 4; ++ni)
          kt_base[(ni >> 1) * 2048 + (ni & 1) * 16 + c] = (__bf16)(v[ni] * sc);
      } else {
        __bf16* drow = ((which == 0) ? qb : vb) + ((size_t)((b2 * 16 + h) * 2048 + lpos)) * 64;
#pragma unroll
        for (int ni = 0; ni < 4; ++ni)
          drow[ni * 16 + c] = (__bf16)(v[ni] * sc);
      }
    }
  }
}

// ---------------------------------------------------------------- V transpose to tile-slot layout
__global__ __launch_bounds__(256)
void vtrans_kernel(const __bf16* __restrict__ vb, __bf16* __restrict__ vtp) {
  __shared__ __attribute__((aligned(16))) __bf16 Vs[4][64 * 64];
  const int w = threadIdx.x >> 6, lane = threadIdx.x & 63;
  const int idx = blockIdx.x * 4 + w;
  const int bh = idx >> 5, tile = idx & 31;
  const __bf16* src = vb + ((size_t)bh * 2048 + tile * 64) * 64;
#pragma unroll
  for (int s = 0; s < 8; ++s)
    gld16((char*)&Vs[w][0] + s * 1024, (const char*)src + s * 1024 + lane * 16);
  __syncthreads();
  __bf16* outb = vtp + (size_t)idx * 4096;
#pragma unroll
  for (int r = 0; r < 8; ++r) {
    const int o = r * 512 + lane * 8;
    const int hd = (o >> 5) & 63;
    const int sl0 = ((o >> 11) << 5) | (o & 31);
    bf16x8 pk;
#pragma unroll
    for (int i = 0; i < 8; ++i) {
      const int slot = sl0 + i;
      const int key = (slot & 3) * 16 + (slot >> 2);
      pk[i] = Vs[w][key * 64 + hd];
    }
    *(bf16x8*)(outb + o) = pk;
  }
}

// ---------------------------------------------------------------- bias rearrange (coalesced, LDS-tiled)
// block = (rb, cg): bias rows [rb*32,+32) cols [cg*256,+256) -> btr[(rb*32+kti)*64+lane][32]
__global__ __launch_bounds__(256)
void btrans_kernel(const float* __restrict__ bias, __bf16* __restrict__ btr) {
  __shared__ __bf16 T[32][264];
  const int tid = threadIdx.x;
  const int rb = blockIdx.x >> 3, cg = blockIdx.x & 7;
  const float* src = bias + (size_t)(rb * 32) * 2048 + cg * 256;
#pragma unroll
  for (int i = 0; i < 8; ++i) {
    const int u = i * 256 + tid;
    const int r = u >> 6, c4 = (u & 63) * 4;
    const float4 v = *(const float4*)(src + (size_t)r * 2048 + c4);
    T[r][c4 + 0] = (__bf16)(v.x * LOG2E);
    T[r][c4 + 1] = (__bf16)(v.y * LOG2E);
    T[r][c4 + 2] = (__bf16)(v.z * LOG2E);
    T[r][c4 + 3] = (__bf16)(v.w * LOG2E);
  }
  __syncthreads();
  const int ktl = tid >> 6;              // local tile 0..3
  const int lane = tid & 63, g = lane >> 4, c = lane & 15;
  __bf16 outv[32];
#pragma unroll
  for (int v = 0; v < 32; ++v) {
    const int mi = v >> 4, ni = (v >> 2) & 3, j = v & 3;
    outv[v] = T[mi * 16 + g * 4 + j][ktl * 64 + ni * 16 + c];
  }
  __bf16* dst = btr + ((size_t)(rb * 32 + cg * 4 + ktl) * 64 + lane) * 32;
#pragma unroll
  for (int i = 0; i < 4; ++i)
    *(bf16x8*)(dst + i * 8) = *(bf16x8*)(outv + i * 8);
}

// ---------------------------------------------------------------- flash attention v4 (K-split x2)
#define LOADK(t, K) {                                                          \
  const char* _b = kp + (size_t)(t) * 8192 + laneoff;                          \
  _Pragma("unroll")                                                            \
  for (int f = 0; f < 8; ++f)                                                  \
    K[f] = *(const bf16x8*)(_b + (f & 1) * 4096 + (f >> 1) * 1024);            \
}
#define LOADBIAS(t, BB) {                                                      \
  const char* _b = bp + ((size_t)(t) * 64 + lane) * 64;                        \
  _Pragma("unroll")                                                            \
  for (int i = 0; i < 4; ++i) BB[i] = *(const bf16x8*)(_b + i * 16);           \
}
#define COMPUTE(t, K, BB) {                                                    \
  bf16x8 vf[8];                                                                \
  {                                                                            \
    const char* _b = vp + (size_t)(t) * 8192 + laneoff;                        \
    _Pragma("unroll")                                                          \
    for (int f = 0; f < 8; ++f)                                                \
      vf[f] = *(const bf16x8*)(_b + (f & 1) * 4096 + (f >> 1) * 1024);         \
  }                                                                            \
  f32x4 sacc[2][4];                                                            \
  _Pragma("unroll")                                                            \
  for (int mi = 0; mi < 2; ++mi)                                               \
    _Pragma("unroll")                                                          \
    for (int ni = 0; ni < 4; ++ni) {                                           \
      f32x4 s_ = (f32x4)(0.0f);                                                \
      s_ = __builtin_amdgcn_mfma_f32_16x16x32_bf16(qf[mi][0], K[ni * 2 + 0], s_, 0, 0, 0); \
      s_ = __builtin_amdgcn_mfma_f32_16x16x32_bf16(qf[mi][1], K[ni * 2 + 1], s_, 0, 0, 0); \
      sacc[mi][ni] = s_;                                                       \
    }                                                                          \
  _Pragma("unroll")                                                            \
  for (int mi = 0; mi < 2; ++mi)                                               \
    _Pragma("unroll")                                                          \
    for (int j = 0; j < 4; ++j) {                                              \
      const float p0 = __builtin_amdgcn_exp2f(sacc[mi][0][j] + (float)BB[(mi * 16 + 0 + j) >> 3][(mi * 16 + 0 + j) & 7]);  \
      const float p1 = __builtin_amdgcn_exp2f(sacc[mi][1][j] + (float)BB[(mi * 16 + 4 + j) >> 3][(mi * 16 + 4 + j) & 7]);  \
      const float p2 = __builtin_amdgcn_exp2f(sacc[mi][2][j] + (float)BB[(mi * 16 + 8 + j) >> 3][(mi * 16 + 8 + j) & 7]);  \
      const float p3 = __builtin_amdgcn_exp2f(sacc[mi][3][j] + (float)BB[(mi * 16 + 12 + j) >> 3][(mi * 16 + 12 + j) & 7]);\
      lsum[mi][j] += (p0 + p1) + (p2 + p3);                                    \
      bf16x4 pk;                                                               \
      pk[0] = (__bf16)p0; pk[1] = (__bf16)p1; pk[2] = (__bf16)p2; pk[3] = (__bf16)p3; \
      *(bf16x4*)&Ps[c >> 3][mi * 16 + g * 4 + j][(c & 7) * 4] = pk;            \
    }                                                                          \
  bf16x8 pf[2][2];                                                             \
  _Pragma("unroll")                                                            \
  for (int mi = 0; mi < 2; ++mi)                                               \
    _Pragma("unroll")                                                          \
    for (int ks = 0; ks < 2; ++ks)                                             \
      pf[mi][ks] = *(const bf16x8*)&Ps[ks][mi * 16 + c][g * 8];                \
  _Pragma("unroll")                                                            \
  for (int mi = 0; mi < 2; ++mi)                                               \
    _Pragma("unroll")                                                          \
    for (int ni = 0; ni < 4; ++ni) {                                           \
      oacc[mi][ni] = __builtin_amdgcn_mfma_f32_16x16x32_bf16(pf[mi][0], vf[ni * 2 + 0], oacc[mi][ni], 0, 0, 0); \
      oacc[mi][ni] = __builtin_amdgcn_mfma_f32_16x16x32_bf16(pf[mi][1], vf[ni * 2 + 1], oacc[mi][ni], 0, 0, 0); \
    }                                                                          \
}

__global__ __launch_bounds__(64, 4)
void attn_kernel(const __bf16* __restrict__ qb, const __bf16* __restrict__ ktp,
                 const __bf16* __restrict__ vtp, const __bf16* __restrict__ btr,
                 float* __restrict__ pO, float* __restrict__ pl) {
  __shared__ __attribute__((aligned(16))) __bf16 Ps[2][32][32];  // 4KB, wave-private
  const int lane = threadIdx.x;
  const int c = lane & 15, g = lane >> 4;
  const int idx = blockIdx.x;                       // half*2048 + qt*32 + bh
  const int bh = idx & 31, qt = (idx >> 5) & 63, half = idx >> 11;
  const int rg = idx & 2047;                        // qt*32 + bh
  const __bf16* qh = qb + (size_t)bh * (2048 * 64);
  const char* kp = (const char*)ktp + (size_t)bh * (32 * 8192);
  const char* vp = (const char*)vtp + (size_t)bh * (32 * 8192);
  const char* bp = (const char*)btr + (size_t)qt * (32 * 64 * 64);
  const int q0 = qt * 32;
  const int laneoff = c * 64 + g * 16;

  bf16x8 qf[2][2];
#pragma unroll
  for (int mi = 0; mi < 2; ++mi)
#pragma unroll
    for (int ks = 0; ks < 2; ++ks)
      qf[mi][ks] = *(const bf16x8*)(qh + (size_t)(q0 + mi * 16 + c) * 64 + ks * 32 + g * 8);

  f32x4 oacc[2][4];
  float lsum[2][4];
#pragma unroll
  for (int mi = 0; mi < 2; ++mi)
#pragma unroll
    for (int ni = 0; ni < 4; ++ni) oacc[mi][ni] = (f32x4)(0.0f);
#pragma unroll
  for (int mi = 0; mi < 2; ++mi)
#pragma unroll
    for (int j = 0; j < 4; ++j) lsum[mi][j] = 0.0f;

  const int t0 = half * 16;
  bf16x8 kA[8], kB[8], bA[4], bB[4];
  LOADK(t0, kA); LOADBIAS(t0, bA);
  for (int t = t0; t < t0 + 16; t += 2) {
    LOADK(t + 1, kB); LOADBIAS(t + 1, bB);
    COMPUTE(t, kA, bA);
    if (t + 2 < t0 + 16) { LOADK(t + 2, kA); LOADBIAS(t + 2, bA); }
    COMPUTE(t + 1, kB, bB);
  }

  float* po = pO + (size_t)rg * 2048;
#pragma unroll
  for (int mi = 0; mi < 2; ++mi)
#pragma unroll
    for (int j = 0; j < 4; ++j) {
      float l = lsum[mi][j];
      l += __shfl_xor(l, 1, 64);
      l += __shfl_xor(l, 2, 64);
      l += __shfl_xor(l, 4, 64);
      l += __shfl_xor(l, 8, 64);
      const int row = mi * 16 + g * 4 + j;
      if (c == 0) atomicAdd(&pl[(size_t)rg * 32 + row], l);
#pragma unroll
      for (int ni = 0; ni < 4; ++ni)
        atomicAdd(&po[row * 64 + ni * 16 + c], oacc[mi][ni][j]);
    }
}

// ---------------------------------------------------------------- combine partials -> oupb bf16
__global__ __launch_bounds__(256)
void combine_kernel(const float* __restrict__ pO, const float* __restrict__ pl,
                    __bf16* __restrict__ oupb) {
  const int rg = blockIdx.x;
  const int bh = rg & 31, qt = rg >> 5;
  const int b2 = bh >> 4, h = bh & 15;
  const int tid = threadIdx.x;
  const int row = tid >> 3, hd0 = (tid & 7) * 8;
  const float inv = 1.0f / pl[(size_t)rg * 32 + row];
  const float* p = pO + (size_t)rg * 2048 + row * 64 + hd0;
  const float4 a = *(const float4*)p;
  const float4 b = *(const float4*)(p + 4);
  bf16x8 o;
  o[0] = (__bf16)(a.x * inv); o[1] = (__bf16)(a.y * inv);
  o[2] = (__bf16)(a.z * inv); o[3] = (__bf16)(a.w * inv);
  o[4] = (__bf16)(b.x * inv); o[5] = (__bf16)(b.y * inv);
  o[6] = (__bf16)(b.z * inv); o[7] = (__bf16)(b.w * inv);
  *(bf16x8*)(oupb + ((size_t)(b2 * 2048 + qt * 32 + row) * 16 + h) * 64 + hd0) = o;
}

// ---------------------------------------------------------------- proj GEMM (64x128 tiles)
__global__ __launch_bounds__(256, 2)
void gemm_proj_kernel(const __bf16* __restrict__ A, const __bf16* __restrict__ B,
                      const float* __restrict__ b_proj, float* __restrict__ out) {
  __shared__ __attribute__((aligned(16))) __bf16 As[64 * 32];
  __shared__ __attribute__((aligned(16))) __bf16 Bs[128 * 32];
  const int tid = threadIdx.x;
  const int w = tid >> 6, lane = tid & 63;
  const int c = lane & 15, g = lane >> 4;
  const int m0 = blockIdx.y * 64, n0 = blockIdx.x * 128;
  const int wm = (w >> 1) * 32, wn = (w & 1) * 64;
  f32x4 acc[2][4];
#pragma unroll
  for (int i = 0; i < 2; ++i)
#pragma unroll
    for (int j = 0; j < 4; ++j) acc[i][j] = (f32x4)(0.0f);

  const int r_row = lane >> 2;
  const int r_col = (lane & 3) * 16;
  const char* Abase = (const char*)A + (size_t)m0 * 2048;
  const char* Bbase = (const char*)B + (size_t)n0 * 2048;

  for (int kt = 0; kt < 1024; kt += 32) {
    {
      const int row = w * 16 + r_row;
      gld16((char*)As + w * 1024, Abase + (size_t)row * 2048 + kt * 2 + r_col);
    }
#pragma unroll
    for (int s = 0; s < 2; ++s) {
      const int R = w * 2 + s;
      const int row = R * 16 + r_row;
      gld16((char*)Bs + R * 1024, Bbase + (size_t)row * 2048 + kt * 2 + r_col);
    }
    __syncthreads();
    bf16x8 af[2], bfr[4];
#pragma unroll
    for (int i = 0; i < 2; ++i)
      af[i] = *(const bf16x8*)((const char*)As + (wm + i * 16 + c) * 64 + g * 16);
#pragma unroll
    for (int i = 0; i < 4; ++i)
      bfr[i] = *(const bf16x8*)((const char*)Bs + (wn + i * 16 + c) * 64 + g * 16);
#pragma unroll
    for (int mi = 0; mi < 2; ++mi)
#pragma unroll
      for (int ni = 0; ni < 4; ++ni)
        acc[mi][ni] = __builtin_amdgcn_mfma_f32_16x16x32_bf16(af[mi], bfr[ni], acc[mi][ni], 0, 0, 0);
    __syncthreads();
  }

  float cbias[4];
#pragma unroll
  for (int ni = 0; ni < 4; ++ni) cbias[ni] = b_proj[n0 + wn + ni * 16 + c];
#pragma unroll
  for (int mi = 0; mi < 2; ++mi)
#pragma unroll
    for (int j = 0; j < 4; ++j) {
      const int m = m0 + wm + mi * 16 + g * 4 + j;
      float* orow = out + (size_t)m * 1024 + n0 + wn;
#pragma unroll
      for (int ni = 0; ni < 4; ++ni)
        orow[ni * 16 + c] = acc[mi][ni][j] + cbias[ni];
    }
}

// ---------------------------------------------------------------- launch
extern "C" void kernel_launch(void* const* d_in, const int* in_sizes, int n_in,
                              void* d_out, int out_size, void* d_ws, size_t ws_size,
                              hipStream_t stream) {
  const float* x         = (const float*)d_in[0];
  const float* attn_bias = (const float*)d_in[1];
  const float* w_qkv     = (const float*)d_in[2];
  const float* q_bias    = (const float*)d_in[3];
  const float* v_bias    = (const float*)d_in[4];
  const float* scale_mul = (const float*)d_in[5];
  const float* w_proj    = (const float*)d_in[6];
  const float* b_proj    = (const float*)d_in[7];
  float* out = (float*)d_out;

  __bf16* xb     = (__bf16*)d_ws;                 // 4M  (aliased as oupb after gemm_qkv)
  __bf16* wqkvb  = xb + 4194304;                  // 3M
  __bf16* wprojb = wqkvb + 3145728;               // 1M
  __bf16* qb     = wprojb + 1048576;              // 4M (q pre-scaled by log2e)
  __bf16* vb     = qb + 4194304;                  // 4M
  __bf16* ktp    = vb + 4194304;                  // 4M (K fragment-tile order)
  __bf16* vtp    = ktp + 4194304;                 // 4M (V slot order)
  __bf16* btr    = vtp + 4194304;                 // 4M (bias, *log2e)
  float*  pO     = (float*)(btr + 4194304);       // 2048*2048 fp32 partial O
  float*  pl     = pO + 2048 * 2048;              // 2048*32 fp32 partial l
  __bf16* oupb   = xb;                            // alias: xb dead after gemm_qkv

  btrans_kernel<<<512, 256, 0, stream>>>(attn_bias, btr);
  cvt_kernel<<<4096, 256, 0, stream>>>(x, xb, 4096 * 1024, 1.0f);
  cvt_kernel<<<3072, 256, 0, stream>>>(w_qkv, wqkvb, 3072 * 1024, 1.0f);
  cvt_kernel<<<1024, 256, 0, stream>>>(w_proj, wprojb, 1024 * 1024, 1.0f);
  hipMemsetAsync(pO, 0, (size_t)(2048 * 2048 + 2048 * 32) * 4, stream);

  gemm_qkv_kernel<<<dim3(24, 32), 256, 0, stream>>>(xb, wqkvb, q_bias, v_bias, scale_mul,
                                                    qb, ktp, vb);
  vtrans_kernel<<<256, 256, 0, stream>>>(vb, vtp);
  attn_kernel<<<4096, 64, 0, stream>>>(qb, ktp, vtp, btr, pO, pl);
  combine_kernel<<<2048, 256, 0, stream>>>(pO, pl, oupb);
  gemm_proj_kernel<<<dim3(8, 64), 256, 0, stream>>>(oupb, wprojb, b_proj, out);
}

// Round 5
// 252.008 us; speedup vs baseline: 1.7880x; 1.7880x over previous
//
#include <hip/hip_runtime.h>
#include <cstdint>
#include <cstddef>
#include <math.h>

typedef __attribute__((ext_vector_type(8))) __bf16 bf16x8;
typedef __attribute__((ext_vector_type(4))) __bf16 bf16x4;
typedef __attribute__((ext_vector_type(4))) float f32x4;

#define AS1 __attribute__((address_space(1)))
#define AS3 __attribute__((address_space(3)))

#define LOG2E 1.4426950408889634f

__device__ __forceinline__ void gld16(void* lds_uniform, const void* gaddr) {
  __builtin_amdgcn_global_load_lds((const AS1 unsigned int*)gaddr,
                                   (AS3 unsigned int*)lds_uniform, 16, 0, 0);
}

// ---------------------------------------------------------------- fp32->bf16 (with scale)
__global__ void cvt_kernel(const float* __restrict__ src, __bf16* __restrict__ dst, int n,
                           float scale) {
  int i = (blockIdx.x * 256 + threadIdx.x) * 4;
  if (i < n) {
    const float4 v = *(const float4*)(src + i);
    bf16x4 o;
    o[0] = (__bf16)(v.x * scale); o[1] = (__bf16)(v.y * scale);
    o[2] = (__bf16)(v.z * scale); o[3] = (__bf16)(v.w * scale);
    *(bf16x4*)(dst + i) = o;
  }
}

// ---------------------------------------------------------------- QKV GEMM
// Fused epilogue: bias, L2-norm, q*=exp(min(sm,ln100))*log2e; K written directly in
// attn fragment-tile order (ktp), Q in row order (qb), V in row order (vb).
__global__ __launch_bounds__(256, 2)
void gemm_qkv_kernel(const __bf16* __restrict__ A, const __bf16* __restrict__ B,
                     const float* __restrict__ q_bias, const float* __restrict__ v_bias,
                     const float* __restrict__ scale_mul,
                     __bf16* __restrict__ qb, __bf16* __restrict__ ktp, __bf16* __restrict__ vb) {
  __shared__ __attribute__((aligned(16))) __bf16 As[128 * 32];
  __shared__ __attribute__((aligned(16))) __bf16 Bs[128 * 32];
  const int tid = threadIdx.x;
  const int w = tid >> 6, lane = tid & 63;
  const int m0 = blockIdx.y * 128, n0 = blockIdx.x * 128;
  const int wm = (w >> 1) * 64, wn = (w & 1) * 64;
  const int c = lane & 15, g = lane >> 4;
  f32x4 acc[4][4];
#pragma unroll
  for (int i = 0; i < 4; ++i)
#pragma unroll
    for (int j = 0; j < 4; ++j) acc[i][j] = (f32x4)(0.0f);

  const int r_row = lane >> 2;
  const int r_col = (lane & 3) * 16;
  const char* Abase = (const char*)A + (size_t)m0 * 2048;
  const char* Bbase = (const char*)B + (size_t)n0 * 2048;

  for (int kt = 0; kt < 1024; kt += 32) {
#pragma unroll
    for (int s = 0; s < 2; ++s) {
      const int R = w * 2 + s;
      const int row = R * 16 + r_row;
      gld16((char*)As + R * 1024, Abase + (size_t)row * 2048 + kt * 2 + r_col);
      gld16((char*)Bs + R * 1024, Bbase + (size_t)row * 2048 + kt * 2 + r_col);
    }
    __syncthreads();
    bf16x8 af[4], bfr[4];
#pragma unroll
    for (int i = 0; i < 4; ++i) {
      af[i]  = *(const bf16x8*)((const char*)As + (wm + i * 16 + c) * 64 + g * 16);
      bfr[i] = *(const bf16x8*)((const char*)Bs + (wn + i * 16 + c) * 64 + g * 16);
    }
#pragma unroll
    for (int mi = 0; mi < 4; ++mi)
#pragma unroll
      for (int ni = 0; ni < 4; ++ni)
        acc[mi][ni] = __builtin_amdgcn_mfma_f32_16x16x32_bf16(af[mi], bfr[ni], acc[mi][ni], 0, 0, 0);
    __syncthreads();
  }

  const int nbase = n0 + wn;
  const int which = nbase >> 10;
  const int h = (nbase >> 6) & 15;
  float smh = 1.0f;
  if (which == 0) smh = __expf(fminf(scale_mul[h], 4.605170185988091f)) * LOG2E;
  float cbias[4];
#pragma unroll
  for (int ni = 0; ni < 4; ++ni) {
    const int n = nbase + ni * 16 + c;
    cbias[ni] = (which == 0) ? q_bias[n] : ((which == 2) ? v_bias[n - 2048] : 0.0f);
  }
#pragma unroll
  for (int mi = 0; mi < 4; ++mi) {
#pragma unroll
    for (int j = 0; j < 4; ++j) {
      const int m = m0 + wm + mi * 16 + g * 4 + j;
      float v[4];
      float ss = 0.0f;
#pragma unroll
      for (int ni = 0; ni < 4; ++ni) { v[ni] = acc[mi][ni][j] + cbias[ni]; ss += v[ni] * v[ni]; }
      ss += __shfl_xor(ss, 1, 64);
      ss += __shfl_xor(ss, 2, 64);
      ss += __shfl_xor(ss, 4, 64);
      ss += __shfl_xor(ss, 8, 64);
      const float sc = (which == 2) ? 1.0f : (rsqrtf(ss) * smh);
      const int b2 = m >> 11, lpos = m & 2047;
      if (which == 1) {
        // K -> fragment-tile order: bh*131072 + (l>>6)*4096 + (hd>>5)*2048 + (l&63)*32 + (hd&31)
        __bf16* kt_base = ktp + (size_t)(b2 * 16 + h) * 131072 +
                          (size_t)(lpos >> 6) * 4096 + (size_t)(lpos & 63) * 32;
#pragma unroll
        for (int ni = 0; ni < 4; ++ni)
          kt_base[(ni >> 1) * 2048 + (ni & 1) * 16 + c] = (__bf16)(v[ni] * sc);
      } else {
        __bf16* drow = ((which == 0) ? qb : vb) + ((size_t)((b2 * 16 + h) * 2048 + lpos)) * 64;
#pragma unroll
        for (int ni = 0; ni < 4; ++ni)
          drow[ni * 16 + c] = (__bf16)(v[ni] * sc);
      }
    }
  }
}

// ---------------------------------------------------------------- V transpose to tile-slot layout
__global__ __launch_bounds__(256)
void vtrans_kernel(const __bf16* __restrict__ vb, __bf16* __restrict__ vtp) {
  __shared__ __attribute__((aligned(16))) __bf16 Vs[4][64 * 64];
  const int w = threadIdx.x >> 6, lane = threadIdx.x & 63;
  const int idx = blockIdx.x * 4 + w;
  const int bh = idx >> 5, tile = idx & 31;
  const __bf16* src = vb + ((size_t)bh * 2048 + tile * 64) * 64;
#pragma unroll
  for (int s = 0; s < 8; ++s)
    gld16((char*)&Vs[w][0] + s * 1024, (const char*)src + s * 1024 + lane * 16);
  __syncthreads();
  __bf16* outb = vtp + (size_t)idx * 4096;
#pragma unroll
  for (int r = 0; r < 8; ++r) {
    const int o = r * 512 + lane * 8;
    const int hd = (o >> 5) & 63;
    const int sl0 = ((o >> 11) << 5) | (o & 31);
    bf16x8 pk;
#pragma unroll
    for (int i = 0; i < 8; ++i) {
      const int slot = sl0 + i;
      const int key = (slot & 3) * 16 + (slot >> 2);
      pk[i] = Vs[w][key * 64 + hd];
    }
    *(bf16x8*)(outb + o) = pk;
  }
}

// ---------------------------------------------------------------- bias rearrange (coalesced, LDS-tiled)
__global__ __launch_bounds__(256)
void btrans_kernel(const float* __restrict__ bias, __bf16* __restrict__ btr) {
  __shared__ __bf16 T[32][264];
  const int tid = threadIdx.x;
  const int rb = blockIdx.x >> 3, cg = blockIdx.x & 7;
  const float* src = bias + (size_t)(rb * 32) * 2048 + cg * 256;
#pragma unroll
  for (int i = 0; i < 8; ++i) {
    const int u = i * 256 + tid;
    const int r = u >> 6, c4 = (u & 63) * 4;
    const float4 v = *(const float4*)(src + (size_t)r * 2048 + c4);
    T[r][c4 + 0] = (__bf16)(v.x * LOG2E);
    T[r][c4 + 1] = (__bf16)(v.y * LOG2E);
    T[r][c4 + 2] = (__bf16)(v.z * LOG2E);
    T[r][c4 + 3] = (__bf16)(v.w * LOG2E);
  }
  __syncthreads();
  const int ktl = tid >> 6;
  const int lane = tid & 63, g = lane >> 4, c = lane & 15;
  __bf16 outv[32];
#pragma unroll
  for (int v = 0; v < 32; ++v) {
    const int mi = v >> 4, ni = (v >> 2) & 3, j = v & 3;
    outv[v] = T[mi * 16 + g * 4 + j][ktl * 64 + ni * 16 + c];
  }
  __bf16* dst = btr + ((size_t)(rb * 32 + cg * 4 + ktl) * 64 + lane) * 32;
#pragma unroll
  for (int i = 0; i < 4; ++i)
    *(bf16x8*)(dst + i * 8) = *(bf16x8*)(outv + i * 8);
}

// ---------------------------------------------------------------- flash attention v5 (K-split x2, disjoint partials, no atomics)
#define LOADK(t, K) {                                                          \
  const char* _b = kp + (size_t)(t) * 8192 + laneoff;                          \
  _Pragma("unroll")                                                            \
  for (int f = 0; f < 8; ++f)                                                  \
    K[f] = *(const bf16x8*)(_b + (f & 1) * 4096 + (f >> 1) * 1024);            \
}
#define LOADBIAS(t, BB) {                                                      \
  const char* _b = bp + ((size_t)(t) * 64 + lane) * 64;                        \
  _Pragma("unroll")                                                            \
  for (int i = 0; i < 4; ++i) BB[i] = *(const bf16x8*)(_b + i * 16);           \
}
#define COMPUTE(t, K, BB) {                                                    \
  bf16x8 vf[8];                                                                \
  {                                                                            \
    const char* _b = vp + (size_t)(t) * 8192 + laneoff;                        \
    _Pragma("unroll")                                                          \
    for (int f = 0; f < 8; ++f)                                                \
      vf[f] = *(const bf16x8*)(_b + (f & 1) * 4096 + (f >> 1) * 1024);         \
  }                                                                            \
  f32x4 sacc[2][4];                                                            \
  _Pragma("unroll")                                                            \
  for (int mi = 0; mi < 2; ++mi)                                               \
    _Pragma("unroll")                                                          \
    for (int ni = 0; ni < 4; ++ni) {                                           \
      f32x4 s_ = (f32x4)(0.0f);                                                \
      s_ = __builtin_amdgcn_mfma_f32_16x16x32_bf16(qf[mi][0], K[ni * 2 + 0], s_, 0, 0, 0); \
      s_ = __builtin_amdgcn_mfma_f32_16x16x32_bf16(qf[mi][1], K[ni * 2 + 1], s_, 0, 0, 0); \
      sacc[mi][ni] = s_;                                                       \
    }                                                                          \
  _Pragma("unroll")                                                            \
  for (int mi = 0; mi < 2; ++mi)                                               \
    _Pragma("unroll")                                                          \
    for (int j = 0; j < 4; ++j) {                                              \
      const float p0 = __builtin_amdgcn_exp2f(sacc[mi][0][j] + (float)BB[(mi * 16 + 0 + j) >> 3][(mi * 16 + 0 + j) & 7]);  \
      const float p1 = __builtin_amdgcn_exp2f(sacc[mi][1][j] + (float)BB[(mi * 16 + 4 + j) >> 3][(mi * 16 + 4 + j) & 7]);  \
      const float p2 = __builtin_amdgcn_exp2f(sacc[mi][2][j] + (float)BB[(mi * 16 + 8 + j) >> 3][(mi * 16 + 8 + j) & 7]);  \
      const float p3 = __builtin_amdgcn_exp2f(sacc[mi][3][j] + (float)BB[(mi * 16 + 12 + j) >> 3][(mi * 16 + 12 + j) & 7]);\
      lsum[mi][j] += (p0 + p1) + (p2 + p3);                                    \
      bf16x4 pk;                                                               \
      pk[0] = (__bf16)p0; pk[1] = (__bf16)p1; pk[2] = (__bf16)p2; pk[3] = (__bf16)p3; \
      *(bf16x4*)&Ps[c >> 3][mi * 16 + g * 4 + j][(c & 7) * 4] = pk;            \
    }                                                                          \
  bf16x8 pf[2][2];                                                             \
  _Pragma("unroll")                                                            \
  for (int mi = 0; mi < 2; ++mi)                                               \
    _Pragma("unroll")                                                          \
    for (int ks = 0; ks < 2; ++ks)                                             \
      pf[mi][ks] = *(const bf16x8*)&Ps[ks][mi * 16 + c][g * 8];                \
  _Pragma("unroll")                                                            \
  for (int mi = 0; mi < 2; ++mi)                                               \
    _Pragma("unroll")                                                          \
    for (int ni = 0; ni < 4; ++ni) {                                           \
      oacc[mi][ni] = __builtin_amdgcn_mfma_f32_16x16x32_bf16(pf[mi][0], vf[ni * 2 + 0], oacc[mi][ni], 0, 0, 0); \
      oacc[mi][ni] = __builtin_amdgcn_mfma_f32_16x16x32_bf16(pf[mi][1], vf[ni * 2 + 1], oacc[mi][ni], 0, 0, 0); \
    }                                                                          \
}

__global__ __launch_bounds__(64, 2)   // (64,2): 116 VGPR, no spill (R3-verified); HW fits 4 waves/SIMD
void attn_kernel(const __bf16* __restrict__ qb, const __bf16* __restrict__ ktp,
                 const __bf16* __restrict__ vtp, const __bf16* __restrict__ btr,
                 float* __restrict__ pO, float* __restrict__ pl) {
  __shared__ __attribute__((aligned(16))) __bf16 Ps[2][32][32];  // 4KB, wave-private
  const int lane = threadIdx.x;
  const int c = lane & 15, g = lane >> 4;
  const int idx = blockIdx.x;                       // half*2048 + qt*32 + bh
  const int bh = idx & 31, qt = (idx >> 5) & 63, half = idx >> 11;
  const int rg = idx & 2047;
  const __bf16* qh = qb + (size_t)bh * (2048 * 64);
  const char* kp = (const char*)ktp + (size_t)bh * (32 * 8192);
  const char* vp = (const char*)vtp + (size_t)bh * (32 * 8192);
  const char* bp = (const char*)btr + (size_t)qt * (32 * 64 * 64);
  const int q0 = qt * 32;
  const int laneoff = c * 64 + g * 16;

  bf16x8 qf[2][2];
#pragma unroll
  for (int mi = 0; mi < 2; ++mi)
#pragma unroll
    for (int ks = 0; ks < 2; ++ks)
      qf[mi][ks] = *(const bf16x8*)(qh + (size_t)(q0 + mi * 16 + c) * 64 + ks * 32 + g * 8);

  f32x4 oacc[2][4];
  float lsum[2][4];
#pragma unroll
  for (int mi = 0; mi < 2; ++mi)
#pragma unroll
    for (int ni = 0; ni < 4; ++ni) oacc[mi][ni] = (f32x4)(0.0f);
#pragma unroll
  for (int mi = 0; mi < 2; ++mi)
#pragma unroll
    for (int j = 0; j < 4; ++j) lsum[mi][j] = 0.0f;

  const int t0 = half * 16;
  bf16x8 kA[8], kB[8], bA[4], bB[4];
  LOADK(t0, kA); LOADBIAS(t0, bA);
  for (int t = t0; t < t0 + 16; t += 2) {
    LOADK(t + 1, kB); LOADBIAS(t + 1, bB);
    COMPUTE(t, kA, bA);
    if (t + 2 < t0 + 16) { LOADK(t + 2, kA); LOADBIAS(t + 2, bA); }
    COMPUTE(t + 1, kB, bB);
  }

  // disjoint partial stores (no atomics): pO[half][rg][row][hd], pl[half][rg][row]
  float* po  = pO + ((size_t)half * 2048 + rg) * 2048;
  float* plp = pl + ((size_t)half * 2048 + rg) * 32;
#pragma unroll
  for (int mi = 0; mi < 2; ++mi)
#pragma unroll
    for (int j = 0; j < 4; ++j) {
      float l = lsum[mi][j];
      l += __shfl_xor(l, 1, 64);
      l += __shfl_xor(l, 2, 64);
      l += __shfl_xor(l, 4, 64);
      l += __shfl_xor(l, 8, 64);
      const int row = mi * 16 + g * 4 + j;
      if (c == 0) plp[row] = l;
#pragma unroll
      for (int ni = 0; ni < 4; ++ni)
        po[row * 64 + ni * 16 + c] = oacc[mi][ni][j];
    }
}

// ---------------------------------------------------------------- combine halves -> oupb bf16
__global__ __launch_bounds__(256)
void combine_kernel(const float* __restrict__ pO, const float* __restrict__ pl,
                    __bf16* __restrict__ oupb) {
  const int rg = blockIdx.x;
  const int bh = rg & 31, qt = rg >> 5;
  const int b2 = bh >> 4, h = bh & 15;
  const int tid = threadIdx.x;
  const int row = tid >> 3, hd0 = (tid & 7) * 8;
  const float l = pl[(size_t)rg * 32 + row] + pl[(size_t)(2048 + rg) * 32 + row];
  const float inv = 1.0f / l;
  const float* p0 = pO + (size_t)rg * 2048 + row * 64 + hd0;
  const float* p1 = p0 + (size_t)2048 * 2048;
  const float4 a0 = *(const float4*)p0;
  const float4 b0 = *(const float4*)(p0 + 4);
  const float4 a1 = *(const float4*)p1;
  const float4 b1 = *(const float4*)(p1 + 4);
  bf16x8 o;
  o[0] = (__bf16)((a0.x + a1.x) * inv); o[1] = (__bf16)((a0.y + a1.y) * inv);
  o[2] = (__bf16)((a0.z + a1.z) * inv); o[3] = (__bf16)((a0.w + a1.w) * inv);
  o[4] = (__bf16)((b0.x + b1.x) * inv); o[5] = (__bf16)((b0.y + b1.y) * inv);
  o[6] = (__bf16)((b0.z + b1.z) * inv); o[7] = (__bf16)((b0.w + b1.w) * inv);
  *(bf16x8*)(oupb + ((size_t)(b2 * 2048 + qt * 32 + row) * 16 + h) * 64 + hd0) = o;
}

// ---------------------------------------------------------------- proj GEMM (64x128 tiles)
__global__ __launch_bounds__(256, 2)
void gemm_proj_kernel(const __bf16* __restrict__ A, const __bf16* __restrict__ B,
                      const float* __restrict__ b_proj, float* __restrict__ out) {
  __shared__ __attribute__((aligned(16))) __bf16 As[64 * 32];
  __shared__ __attribute__((aligned(16))) __bf16 Bs[128 * 32];
  const int tid = threadIdx.x;
  const int w = tid >> 6, lane = tid & 63;
  const int c = lane & 15, g = lane >> 4;
  const int m0 = blockIdx.y * 64, n0 = blockIdx.x * 128;
  const int wm = (w >> 1) * 32, wn = (w & 1) * 64;
  f32x4 acc[2][4];
#pragma unroll
  for (int i = 0; i < 2; ++i)
#pragma unroll
    for (int j = 0; j < 4; ++j) acc[i][j] = (f32x4)(0.0f);

  const int r_row = lane >> 2;
  const int r_col = (lane & 3) * 16;
  const char* Abase = (const char*)A + (size_t)m0 * 2048;
  const char* Bbase = (const char*)B + (size_t)n0 * 2048;

  for (int kt = 0; kt < 1024; kt += 32) {
    {
      const int row = w * 16 + r_row;
      gld16((char*)As + w * 1024, Abase + (size_t)row * 2048 + kt * 2 + r_col);
    }
#pragma unroll
    for (int s = 0; s < 2; ++s) {
      const int R = w * 2 + s;
      const int row = R * 16 + r_row;
      gld16((char*)Bs + R * 1024, Bbase + (size_t)row * 2048 + kt * 2 + r_col);
    }
    __syncthreads();
    bf16x8 af[2], bfr[4];
#pragma unroll
    for (int i = 0; i < 2; ++i)
      af[i] = *(const bf16x8*)((const char*)As + (wm + i * 16 + c) * 64 + g * 16);
#pragma unroll
    for (int i = 0; i < 4; ++i)
      bfr[i] = *(const bf16x8*)((const char*)Bs + (wn + i * 16 + c) * 64 + g * 16);
#pragma unroll
    for (int mi = 0; mi < 2; ++mi)
#pragma unroll
      for (int ni = 0; ni < 4; ++ni)
        acc[mi][ni] = __builtin_amdgcn_mfma_f32_16x16x32_bf16(af[mi], bfr[ni], acc[mi][ni], 0, 0, 0);
    __syncthreads();
  }

  float cbias[4];
#pragma unroll
  for (int ni = 0; ni < 4; ++ni) cbias[ni] = b_proj[n0 + wn + ni * 16 + c];
#pragma unroll
  for (int mi = 0; mi < 2; ++mi)
#pragma unroll
    for (int j = 0; j < 4; ++j) {
      const int m = m0 + wm + mi * 16 + g * 4 + j;
      float* orow = out + (size_t)m * 1024 + n0 + wn;
#pragma unroll
      for (int ni = 0; ni < 4; ++ni)
        orow[ni * 16 + c] = acc[mi][ni][j] + cbias[ni];
    }
}

// ---------------------------------------------------------------- launch
extern "C" void kernel_launch(void* const* d_in, const int* in_sizes, int n_in,
                              void* d_out, int out_size, void* d_ws, size_t ws_size,
                              hipStream_t stream) {
  const float* x         = (const float*)d_in[0];
  const float* attn_bias = (const float*)d_in[1];
  const float* w_qkv     = (const float*)d_in[2];
  const float* q_bias    = (const float*)d_in[3];
  const float* v_bias    = (const float*)d_in[4];
  const float* scale_mul = (const float*)d_in[5];
  const float* w_proj    = (const float*)d_in[6];
  const float* b_proj    = (const float*)d_in[7];
  float* out = (float*)d_out;

  __bf16* xb     = (__bf16*)d_ws;                 // 8MB (aliased as oupb after gemm_qkv)
  __bf16* wqkvb  = xb + 4194304;                  // 6MB
  __bf16* wprojb = wqkvb + 3145728;               // 2MB
  __bf16* qb     = wprojb + 1048576;              // 8MB (q pre-scaled by log2e)
  __bf16* ktp    = qb + 4194304;                  // 8MB (K fragment-tile order)
  __bf16* vtp    = ktp + 4194304;                 // 8MB (V slot order)
  __bf16* btr    = vtp + 4194304;                 // 8MB (bias, *log2e)
  __bf16* vb     = btr + 4194304;                 // 8MB (V row order; dead after vtrans)
  float*  pO     = (float*)vb;                    // 32MB, aliases vb (attn runs after vtrans)
  float*  pl     = pO + 2 * 2048 * 2048;          // 512KB
  __bf16* oupb   = xb;                            // alias: xb dead after gemm_qkv

  btrans_kernel<<<512, 256, 0, stream>>>(attn_bias, btr);
  cvt_kernel<<<4096, 256, 0, stream>>>(x, xb, 4096 * 1024, 1.0f);
  cvt_kernel<<<3072, 256, 0, stream>>>(w_qkv, wqkvb, 3072 * 1024, 1.0f);
  cvt_kernel<<<1024, 256, 0, stream>>>(w_proj, wprojb, 1024 * 1024, 1.0f);

  gemm_qkv_kernel<<<dim3(24, 32), 256, 0, stream>>>(xb, wqkvb, q_bias, v_bias, scale_mul,
                                                    qb, ktp, vb);
  vtrans_kernel<<<256, 256, 0, stream>>>(vb, vtp);
  attn_kernel<<<4096, 64, 0, stream>>>(qb, ktp, vtp, btr, pO, pl);
  combine_kernel<<<2048, 256, 0, stream>>>(pO, pl, oupb);
  gemm_proj_kernel<<<dim3(8, 64), 256, 0, stream>>>(oupb, wprojb, b_proj, out);
}